// Round 4
// baseline (674.126 us; speedup 1.0000x reference)
//
#include <hip/hip_runtime.h>

typedef unsigned short u16;
typedef __attribute__((ext_vector_type(8))) short bf16x8;
typedef __attribute__((ext_vector_type(4))) float f32x4;

__device__ inline float bf2f(u16 u) {
    unsigned v = ((unsigned)u) << 16;
    return __builtin_bit_cast(float, v);
}
__device__ inline u16 f2bf(float f) {
    unsigned u = __builtin_bit_cast(unsigned, f);
    u += 0x7fff + ((u >> 16) & 1);   // RNE
    return (u16)(u >> 16);
}

// async global->LDS, 16B per lane. LDS dest = wave-uniform base + lane*16.
// (validated: round-1 output was bit-identical to register staging)
__device__ inline void gload_lds16(const void* g, void* l) {
    __builtin_amdgcn_global_load_lds(
        (const __attribute__((address_space(1))) unsigned int*)(unsigned long long)g,
        (__attribute__((address_space(3))) unsigned int*)(unsigned)(unsigned long long)l,
        16, 0, 0);
}

// ---------------------------------------------------------------- cast x -> bf16
__global__ __launch_bounds__(256) void cast_x(const float4* __restrict__ x,
                                              u16* __restrict__ xb) {
    long i = (long)blockIdx.x * 256 + threadIdx.x;   // one float4 per thread
    float4 v = x[i];
    u16* o = xb + i * 4;
    o[0] = f2bf(v.x); o[1] = f2bf(v.y); o[2] = f2bf(v.z); o[3] = f2bf(v.w);
}

// ---------------------------------------------------------------- weight fold/transpose (f32 inputs)
// r in [0,512):    WallT[r][kin] = sum_d Wq[kin][h*64+d]*proj[d][f]   (h=r>>5, f=r&31)
// r in [512,1024): same with Wk
// r in [1024,2048):WallT[r][kin] = Wv[kin][r-1024]
// r in [2048,3072):WoT[r-2048][kin] = Wo[kin][r-2048]
__global__ __launch_bounds__(256) void fold_weights(
    const float* __restrict__ Wq, const float* __restrict__ Wk,
    const float* __restrict__ Wv, const float* __restrict__ Wo,
    const float* __restrict__ bq, const float* __restrict__ bk,
    const float* __restrict__ bv, const float* __restrict__ proj,
    u16* __restrict__ WallT, u16* __restrict__ WoT, float* __restrict__ bias_all)
{
    const int r = blockIdx.x;
    const int tid = threadIdx.x;
    if (r < 1024) {
        const float* W  = (r < 512) ? Wq : Wk;
        const float* bb = (r < 512) ? bq : bk;
        const int h = (r & 511) >> 5, f = r & 31;
        __shared__ float pcol[64];
        if (tid < 64) pcol[tid] = proj[tid * 32 + f];
        __syncthreads();
        for (int it = 0; it < 4; it++) {
            const int kin = it * 256 + tid;
            const float* wrow = W + (long)kin * 1024 + h * 64;
            float acc = 0.f;
            #pragma unroll
            for (int d = 0; d < 64; d += 4) {
                float4 w = *(const float4*)(wrow + d);
                acc += w.x * pcol[d] + w.y * pcol[d + 1] + w.z * pcol[d + 2] + w.w * pcol[d + 3];
            }
            WallT[(long)r * 1024 + kin] = f2bf(acc);
        }
        if (tid == 0) {
            float a = 0.f;
            for (int d = 0; d < 64; d++) a += bb[h * 64 + d] * pcol[d];
            bias_all[r] = a;
        }
    } else if (r < 2048) {
        const int c = r - 1024;
        for (int it = 0; it < 4; it++) {
            const int kin = it * 256 + tid;
            WallT[(long)r * 1024 + kin] = f2bf(Wv[(long)kin * 1024 + c]);
        }
        if (tid == 0) bias_all[r] = bv[c];
    } else {
        const int c = r - 2048;
        for (int it = 0; it < 4; it++) {
            const int kin = it * 256 + tid;
            WoT[(long)c * 1024 + kin] = f2bf(Wo[(long)kin * 1024 + c]);
        }
    }
}

// ---------------------------------------------------------------- 128x128 bf16 MFMA GEMM, B transposed [N][K]
// m97 structure: async global->LDS width-16 staging, unpadded LDS (required
// for global_load_lds lane-contiguity). OutT: u16 (bf16) or float.
template<int NCOLS, bool RELUQK, typename OutT>
__global__ __launch_bounds__(256) void gemm_bt(
    const u16* __restrict__ A, const u16* __restrict__ Bt,
    const float* __restrict__ bias, OutT* __restrict__ C)
{
    constexpr int K = 1024;
    __shared__ alignas(16) u16 As[128 * 32];   // [m][k] row-major
    __shared__ alignas(16) u16 Bs[128 * 32];   // [n][k] row-major
    const int tid = threadIdx.x;
    const int wave = tid >> 6, lane = tid & 63;
    const int wm = wave >> 1, wn = wave & 1;
    const long m0 = (long)blockIdx.x * 128;
    const long n0 = (long)blockIdx.y * 128;

    // staging addressing: lane covers row (lane>>2), cols (lane&3)*8 .. +8
    const u16* Ab = A  + (m0 + wave * 16 + (lane >> 2)) * K + (lane & 3) * 8;
    const u16* Bb = Bt + (n0 + wave * 16 + (lane >> 2)) * K + (lane & 3) * 8;
    u16* lA = &As[(wave * 16) * 32];
    u16* lB = &Bs[(wave * 16) * 32];

    f32x4 acc[4][4] = {};

    // fragment: A[m=lane&15][k=(lane>>4)*8+j]
    const int ar = (wm * 64 + (lane & 15)) * 32 + (lane >> 4) * 8;
    const int br = (wn * 64 + (lane & 15)) * 32 + (lane >> 4) * 8;

    for (int k0 = 0; k0 < K; k0 += 32) {
        __syncthreads();
        gload_lds16(Ab + k0,           lA);
        gload_lds16(Ab + k0 + 64 * K,  lA + 64 * 32);
        gload_lds16(Bb + k0,           lB);
        gload_lds16(Bb + k0 + 64 * K,  lB + 64 * 32);
        __syncthreads();

        bf16x8 af[4], bfv[4];
        #pragma unroll
        for (int t = 0; t < 4; t++) {
            af[t]  = *(const bf16x8*)&As[ar + t * 16 * 32];
            bfv[t] = *(const bf16x8*)&Bs[br + t * 16 * 32];
        }
        #pragma unroll
        for (int mt = 0; mt < 4; mt++)
            #pragma unroll
            for (int nt = 0; nt < 4; nt++)
                acc[mt][nt] = __builtin_amdgcn_mfma_f32_16x16x32_bf16(
                    af[mt], bfv[nt], acc[mt][nt], 0, 0, 0);
    }

    // epilogue: C/D layout col=lane&15, row=(lane>>4)*4+reg  [measured m89/m91]
    const bool dorelu = RELUQK && (n0 < 1024);
    const int cr = wm * 64 + (lane >> 4) * 4;
    const int cc = wn * 64 + (lane & 15);
    #pragma unroll
    for (int nt = 0; nt < 4; nt++) {
        const long gcol = n0 + cc + nt * 16;
        const float bval = bias[gcol];
        #pragma unroll
        for (int mt = 0; mt < 4; mt++) {
            #pragma unroll
            for (int r = 0; r < 4; r++) {
                float c = acc[mt][nt][r] + bval;
                if (dorelu) c = fmaxf(c, 0.f) * 0.17677669529663687f;  // 1/sqrt(32)
                OutT* dst = &C[(m0 + cr + mt * 16 + r) * (long)NCOLS + gcol];
                if constexpr (sizeof(OutT) == 2) *dst = f2bf(c);
                else                             *dst = c;
            }
        }
    }
}

// ---------------------------------------------------------------- kv[b,h,f,d] + ksum[b,h,f]
// Y layout: [16384][2048] bf16, cols 0..511 q', 512..1023 k', 1024..2047 v
__global__ __launch_bounds__(256) void kv_kernel(const u16* __restrict__ Y,
                                                 float* __restrict__ kv,
                                                 float* __restrict__ ksum)
{
    const int bh = blockIdx.x;       // 0..63
    const int chunk = blockIdx.y;    // 0..15  (256 rows each)
    const int b = bh >> 4, h = bh & 15;
    const int tid = threadIdx.x;
    const int f = tid >> 3, dg = (tid & 7) * 8;
    const long rbase = (long)(b * 4096 + chunk * 256) * 2048;
    const u16* kp = Y + rbase + 512  + h * 32 + f;
    const u16* vp = Y + rbase + 1024 + h * 64 + dg;
    float acc[8] = {};
    float ks = 0.f;
    for (int n = 0; n < 256; n++) {
        float kf = bf2f(*kp);
        bf16x8 vv = *(const bf16x8*)vp;
        #pragma unroll
        for (int j = 0; j < 8; j++) acc[j] += kf * bf2f((u16)vv[j]);
        ks += kf;
        kp += 2048; vp += 2048;
    }
    float* kvp = kv + ((long)bh * 32 + f) * 64 + dg;
    #pragma unroll
    for (int j = 0; j < 8; j++) atomicAdd(&kvp[j], acc[j]);
    if ((tid & 7) == 0) atomicAdd(&ksum[bh * 32 + f], ks);
}

// ---------------------------------------------------------------- attn = (q'.kv) / (q'.ksum + eps)
__global__ __launch_bounds__(256) void attn_kernel(const u16* __restrict__ Y,
                                                   const float* __restrict__ kv,
                                                   const float* __restrict__ ksum,
                                                   u16* __restrict__ attn)
{
    const int rh = blockIdx.x * 4 + (threadIdx.x >> 6);   // (row, head) per wave
    const int lane = threadIdx.x & 63;                    // d
    const int row = rh >> 4, h = rh & 15;
    const int b = row >> 12;
    const u16* qp = Y + (long)row * 2048 + h * 32;
    const float* kvp = kv + ((long)(b * 16 + h)) * 2048 + lane;
    const float* ksp = ksum + (b * 16 + h) * 32;
    float acc = 0.f, den = 0.f;
    #pragma unroll
    for (int f = 0; f < 32; f++) {
        float qf = bf2f(qp[f]);
        acc += qf * kvp[f * 64];
        den += qf * ksp[f];
    }
    float z = 1.f / (den + 1e-8f);
    attn[(long)row * 1024 + h * 64 + lane] = f2bf(acc * z);
}

// ---------------------------------------------------------------- launch
extern "C" void kernel_launch(void* const* d_in, const int* in_sizes, int n_in,
                              void* d_out, int out_size, void* d_ws, size_t ws_size,
                              hipStream_t stream)
{
    // Reference dtypes: ALL inputs f32, output f32.
    const float* x    = (const float*)d_in[0];
    const float* Wq   = (const float*)d_in[1];
    const float* bq   = (const float*)d_in[2];
    const float* Wk   = (const float*)d_in[3];
    const float* bk   = (const float*)d_in[4];
    const float* Wv   = (const float*)d_in[5];
    const float* bv   = (const float*)d_in[6];
    const float* proj = (const float*)d_in[7];
    const float* Wo   = (const float*)d_in[8];
    const float* bo   = (const float*)d_in[9];

    // attn aliases xbf (xbf dead after gemm1; attn born after kv_kernel).
    char* w = (char*)d_ws;
    u16*   xbf   = (u16*)  (w);                    // 33,554,432 B  (also attn)
    u16*   attn  = (u16*)  (w);                    // alias of xbf
    u16*   wallT = (u16*)  (w + 33554432);         //  4,194,304 B
    u16*   woT   = (u16*)  (w + 37748736);         //  2,097,152 B
    float* bias  = (float*)(w + 39845888);         //      8,192 B
    float* kv    = (float*)(w + 39854080);         //    524,288 B
    float* ksum  = (float*)(w + 40378368);         //      8,192 B
    u16*   Y     = (u16*)  (w + 40386560);         // 67,108,864 B  (~104.5 MB)

    hipMemsetAsync(kv, 0, 524288 + 8192, stream);  // kv + ksum contiguous

    cast_x<<<16384, 256, 0, stream>>>((const float4*)x, xbf);

    fold_weights<<<3072, 256, 0, stream>>>(Wq, Wk, Wv, Wo, bq, bk, bv, proj,
                                           wallT, woT, bias);

    gemm_bt<2048, true, u16><<<dim3(128, 16), 256, 0, stream>>>(xbf, wallT, bias, Y);

    kv_kernel<<<dim3(64, 16), 256, 0, stream>>>(Y, kv, ksum);

    attn_kernel<<<65536, 256, 0, stream>>>(Y, kv, ksum, attn);

    gemm_bt<1024, false, float><<<dim3(128, 8), 256, 0, stream>>>(attn, woT, bo,
                                                                  (float*)d_out);
}

// Round 5
// 481.240 us; speedup vs baseline: 1.4008x; 1.4008x over previous
//
#include <hip/hip_runtime.h>

typedef unsigned short u16;
typedef __attribute__((ext_vector_type(8))) short bf16x8;
typedef __attribute__((ext_vector_type(4))) float f32x4;

__device__ inline float bf2f(u16 u) {
    unsigned v = ((unsigned)u) << 16;
    return __builtin_bit_cast(float, v);
}
__device__ inline u16 f2bf(float f) {
    unsigned u = __builtin_bit_cast(unsigned, f);
    u += 0x7fff + ((u >> 16) & 1);   // RNE
    return (u16)(u >> 16);
}

// async global->LDS, 16B per lane. LDS dest = wave-uniform base + lane*16.
__device__ inline void gload_lds16(const void* g, void* l) {
    __builtin_amdgcn_global_load_lds(
        (const __attribute__((address_space(1))) unsigned int*)(unsigned long long)g,
        (__attribute__((address_space(3))) unsigned int*)(unsigned)(unsigned long long)l,
        16, 0, 0);
}

// ---------------------------------------------------------------- cast x -> bf16
__global__ __launch_bounds__(256) void cast_x(const float4* __restrict__ x,
                                              u16* __restrict__ xb) {
    long i = (long)blockIdx.x * 256 + threadIdx.x;   // one float4 per thread
    float4 v = x[i];
    u16* o = xb + i * 4;
    o[0] = f2bf(v.x); o[1] = f2bf(v.y); o[2] = f2bf(v.z); o[3] = f2bf(v.w);
}

// ---------------------------------------------------------------- weight fold/transpose (f32 inputs)
__global__ __launch_bounds__(256) void fold_weights(
    const float* __restrict__ Wq, const float* __restrict__ Wk,
    const float* __restrict__ Wv, const float* __restrict__ Wo,
    const float* __restrict__ bq, const float* __restrict__ bk,
    const float* __restrict__ bv, const float* __restrict__ proj,
    u16* __restrict__ WallT, u16* __restrict__ WoT, float* __restrict__ bias_all)
{
    const int r = blockIdx.x;
    const int tid = threadIdx.x;
    if (r < 1024) {
        const float* W  = (r < 512) ? Wq : Wk;
        const float* bb = (r < 512) ? bq : bk;
        const int h = (r & 511) >> 5, f = r & 31;
        __shared__ float pcol[64];
        if (tid < 64) pcol[tid] = proj[tid * 32 + f];
        __syncthreads();
        for (int it = 0; it < 4; it++) {
            const int kin = it * 256 + tid;
            const float* wrow = W + (long)kin * 1024 + h * 64;
            float acc = 0.f;
            #pragma unroll
            for (int d = 0; d < 64; d += 4) {
                float4 w = *(const float4*)(wrow + d);
                acc += w.x * pcol[d] + w.y * pcol[d + 1] + w.z * pcol[d + 2] + w.w * pcol[d + 3];
            }
            WallT[(long)r * 1024 + kin] = f2bf(acc);
        }
        if (tid == 0) {
            float a = 0.f;
            for (int d = 0; d < 64; d++) a += bb[h * 64 + d] * pcol[d];
            bias_all[r] = a;
        }
    } else if (r < 2048) {
        const int c = r - 1024;
        for (int it = 0; it < 4; it++) {
            const int kin = it * 256 + tid;
            WallT[(long)r * 1024 + kin] = f2bf(Wv[(long)kin * 1024 + c]);
        }
        if (tid == 0) bias_all[r] = bv[c];
    } else {
        const int c = r - 2048;
        for (int it = 0; it < 4; it++) {
            const int kin = it * 256 + tid;
            WoT[(long)c * 1024 + kin] = f2bf(Wo[(long)kin * 1024 + c]);
        }
    }
}

// ---------------------------------------------------------------- 128x128 bf16 MFMA GEMM, B transposed [N][K]
template<int NCOLS, bool RELUQK, typename OutT>
__global__ __launch_bounds__(256) void gemm_bt(
    const u16* __restrict__ A, const u16* __restrict__ Bt,
    const float* __restrict__ bias, OutT* __restrict__ C)
{
    constexpr int K = 1024;
    __shared__ alignas(16) u16 As[128 * 32];   // [m][k] row-major
    __shared__ alignas(16) u16 Bs[128 * 32];   // [n][k] row-major
    const int tid = threadIdx.x;
    const int wave = tid >> 6, lane = tid & 63;
    const int wm = wave >> 1, wn = wave & 1;
    const long m0 = (long)blockIdx.x * 128;
    const long n0 = (long)blockIdx.y * 128;

    const u16* Ab = A  + (m0 + wave * 16 + (lane >> 2)) * K + (lane & 3) * 8;
    const u16* Bb = Bt + (n0 + wave * 16 + (lane >> 2)) * K + (lane & 3) * 8;
    u16* lA = &As[(wave * 16) * 32];
    u16* lB = &Bs[(wave * 16) * 32];

    f32x4 acc[4][4] = {};

    const int ar = (wm * 64 + (lane & 15)) * 32 + (lane >> 4) * 8;
    const int br = (wn * 64 + (lane & 15)) * 32 + (lane >> 4) * 8;

    for (int k0 = 0; k0 < K; k0 += 32) {
        __syncthreads();
        gload_lds16(Ab + k0,           lA);
        gload_lds16(Ab + k0 + 64 * K,  lA + 64 * 32);
        gload_lds16(Bb + k0,           lB);
        gload_lds16(Bb + k0 + 64 * K,  lB + 64 * 32);
        __syncthreads();

        bf16x8 af[4], bfv[4];
        #pragma unroll
        for (int t = 0; t < 4; t++) {
            af[t]  = *(const bf16x8*)&As[ar + t * 16 * 32];
            bfv[t] = *(const bf16x8*)&Bs[br + t * 16 * 32];
        }
        #pragma unroll
        for (int mt = 0; mt < 4; mt++)
            #pragma unroll
            for (int nt = 0; nt < 4; nt++)
                acc[mt][nt] = __builtin_amdgcn_mfma_f32_16x16x32_bf16(
                    af[mt], bfv[nt], acc[mt][nt], 0, 0, 0);
    }

    const bool dorelu = RELUQK && (n0 < 1024);
    const int cr = wm * 64 + (lane >> 4) * 4;
    const int cc = wn * 64 + (lane & 15);
    #pragma unroll
    for (int nt = 0; nt < 4; nt++) {
        const long gcol = n0 + cc + nt * 16;
        const float bval = bias[gcol];
        #pragma unroll
        for (int mt = 0; mt < 4; mt++) {
            #pragma unroll
            for (int r = 0; r < 4; r++) {
                float c = acc[mt][nt][r] + bval;
                if (dorelu) c = fmaxf(c, 0.f) * 0.17677669529663687f;  // 1/sqrt(32)
                OutT* dst = &C[(m0 + cr + mt * 16 + r) * (long)NCOLS + gcol];
                if constexpr (sizeof(OutT) == 2) *dst = f2bf(c);
                else                             *dst = c;
            }
        }
    }
}

// ---------------------------------------------------------------- kv[b,h,f,d] + ksum[b,h,f]
__global__ __launch_bounds__(256) void kv_kernel(const u16* __restrict__ Y,
                                                 float* __restrict__ kv,
                                                 float* __restrict__ ksum)
{
    const int bh = blockIdx.x;       // 0..63
    const int chunk = blockIdx.y;    // 0..15  (256 rows each)
    const int b = bh >> 4, h = bh & 15;
    const int tid = threadIdx.x;
    const int f = tid >> 3, dg = (tid & 7) * 8;
    const long rbase = (long)(b * 4096 + chunk * 256) * 2048;
    const u16* kp = Y + rbase + 512  + h * 32 + f;
    const u16* vp = Y + rbase + 1024 + h * 64 + dg;
    float acc[8] = {};
    float ks = 0.f;
    for (int n = 0; n < 256; n++) {
        float kf = bf2f(*kp);
        bf16x8 vv = *(const bf16x8*)vp;
        #pragma unroll
        for (int j = 0; j < 8; j++) acc[j] += kf * bf2f((u16)vv[j]);
        ks += kf;
        kp += 2048; vp += 2048;
    }
    float* kvp = kv + ((long)bh * 32 + f) * 64 + dg;
    #pragma unroll
    for (int j = 0; j < 8; j++) atomicAdd(&kvp[j], acc[j]);
    if ((tid & 7) == 0) atomicAdd(&ksum[bh * 32 + f], ks);
}

// ---------------------------------------------------------------- attn v2: block-tiled, kv in registers
// grid (bh=64, row-chunks=64), block 256. Lane = output dim d.
// Each lane holds kv[:,d] (32 f32) in VGPRs; q tile (64x32 bf16) in LDS;
// per-wave denominators precomputed into LDS.
__global__ __launch_bounds__(256) void attn_v2(const u16* __restrict__ Y,
                                               const float* __restrict__ kv,
                                               const float* __restrict__ ksum,
                                               u16* __restrict__ attn)
{
    __shared__ alignas(16) u16 qs[64 * 32];   // [local_row][f]
    __shared__ float zs[64];                  // 1/(den+eps) per local row
    const int tid = threadIdx.x;
    const int bh = blockIdx.x;
    const int b = bh >> 4, h = bh & 15;
    const long row0 = (long)b * 4096 + (long)blockIdx.y * 64;

    // stage q tile: one bf16x8 per thread
    {
        const int lr = tid >> 2, c = (tid & 3) * 8;
        *(bf16x8*)&qs[lr * 32 + c] =
            *(const bf16x8*)(Y + (row0 + lr) * 2048 + h * 32 + c);
    }

    // preload this lane's kv column into registers (coalesced, L1-broadcast
    // across the 64 row-chunk blocks of this head)
    const int wave = tid >> 6, lane = tid & 63;
    const float* kvg = kv + (long)bh * 2048 + lane;
    float kvreg[32];
    #pragma unroll
    for (int ff = 0; ff < 32; ff++) kvreg[ff] = kvg[ff * 64];

    __syncthreads();

    // denominators: lanes (l&15) of each wave compute rows wave*16+(l&15)
    {
        const int lr = wave * 16 + (lane & 15);
        const float* ks = ksum + bh * 32;
        float den = 0.f;
        #pragma unroll
        for (int fc = 0; fc < 4; fc++) {
            bf16x8 qv = *(const bf16x8*)&qs[lr * 32 + fc * 8];
            #pragma unroll
            for (int j = 0; j < 8; j++) den += bf2f((u16)qv[j]) * ks[fc * 8 + j];
        }
        if (lane < 16) zs[lr] = 1.f / (den + 1e-8f);
    }
    __syncthreads();

    // main: 4 row-groups of 4 rows; kv from regs, q broadcast from LDS
    #pragma unroll
    for (int rg = 0; rg < 4; rg++) {
        const int lr0 = wave * 16 + rg * 4;
        float acc0 = 0.f, acc1 = 0.f, acc2 = 0.f, acc3 = 0.f;
        #pragma unroll
        for (int fc = 0; fc < 4; fc++) {
            bf16x8 q0 = *(const bf16x8*)&qs[(lr0 + 0) * 32 + fc * 8];
            bf16x8 q1 = *(const bf16x8*)&qs[(lr0 + 1) * 32 + fc * 8];
            bf16x8 q2 = *(const bf16x8*)&qs[(lr0 + 2) * 32 + fc * 8];
            bf16x8 q3 = *(const bf16x8*)&qs[(lr0 + 3) * 32 + fc * 8];
            #pragma unroll
            for (int j = 0; j < 8; j++) {
                const float kvf = kvreg[fc * 8 + j];
                acc0 += bf2f((u16)q0[j]) * kvf;
                acc1 += bf2f((u16)q1[j]) * kvf;
                acc2 += bf2f((u16)q2[j]) * kvf;
                acc3 += bf2f((u16)q3[j]) * kvf;
            }
        }
        u16* op = attn + (row0 + lr0) * 1024 + h * 64 + lane;
        op[0]        = f2bf(acc0 * zs[lr0 + 0]);
        op[1024]     = f2bf(acc1 * zs[lr0 + 1]);
        op[2 * 1024] = f2bf(acc2 * zs[lr0 + 2]);
        op[3 * 1024] = f2bf(acc3 * zs[lr0 + 3]);
    }
}

// ---------------------------------------------------------------- launch
extern "C" void kernel_launch(void* const* d_in, const int* in_sizes, int n_in,
                              void* d_out, int out_size, void* d_ws, size_t ws_size,
                              hipStream_t stream)
{
    const float* x    = (const float*)d_in[0];
    const float* Wq   = (const float*)d_in[1];
    const float* bq   = (const float*)d_in[2];
    const float* Wk   = (const float*)d_in[3];
    const float* bk   = (const float*)d_in[4];
    const float* Wv   = (const float*)d_in[5];
    const float* bv   = (const float*)d_in[6];
    const float* proj = (const float*)d_in[7];
    const float* Wo   = (const float*)d_in[8];
    const float* bo   = (const float*)d_in[9];

    char* w = (char*)d_ws;
    u16*   xbf   = (u16*)  (w);                    // 33,554,432 B  (also attn)
    u16*   attn  = (u16*)  (w);                    // alias of xbf
    u16*   wallT = (u16*)  (w + 33554432);         //  4,194,304 B
    u16*   woT   = (u16*)  (w + 37748736);         //  2,097,152 B
    float* bias  = (float*)(w + 39845888);         //      8,192 B
    float* kv    = (float*)(w + 39854080);         //    524,288 B
    float* ksum  = (float*)(w + 40378368);         //      8,192 B
    u16*   Y     = (u16*)  (w + 40386560);         // 67,108,864 B  (~104.5 MB)

    hipMemsetAsync(kv, 0, 524288 + 8192, stream);  // kv + ksum contiguous

    cast_x<<<16384, 256, 0, stream>>>((const float4*)x, xbf);

    fold_weights<<<3072, 256, 0, stream>>>(Wq, Wk, Wv, Wo, bq, bk, bv, proj,
                                           wallT, woT, bias);

    gemm_bt<2048, true, u16><<<dim3(128, 16), 256, 0, stream>>>(xbf, wallT, bias, Y);

    kv_kernel<<<dim3(64, 16), 256, 0, stream>>>(Y, kv, ksum);

    attn_v2<<<dim3(64, 64), 256, 0, stream>>>(Y, kv, ksum, attn);

    gemm_bt<1024, false, float><<<dim3(128, 8), 256, 0, stream>>>(attn, woT, bo,
                                                                  (float*)d_out);
}

// Round 6
// 477.581 us; speedup vs baseline: 1.4115x; 1.0077x over previous
//
#include <hip/hip_runtime.h>

typedef unsigned short u16;
typedef __attribute__((ext_vector_type(8))) short bf16x8;
typedef __attribute__((ext_vector_type(4))) float f32x4;

__device__ inline float bf2f(u16 u) {
    unsigned v = ((unsigned)u) << 16;
    return __builtin_bit_cast(float, v);
}
__device__ inline u16 f2bf(float f) {
    unsigned u = __builtin_bit_cast(unsigned, f);
    u += 0x7fff + ((u >> 16) & 1);   // RNE
    return (u16)(u >> 16);
}

// async global->LDS, 16B per lane. LDS dest = wave-uniform base + lane*16.
__device__ inline void gload_lds16(const void* g, void* l) {
    __builtin_amdgcn_global_load_lds(
        (const __attribute__((address_space(1))) unsigned int*)(unsigned long long)g,
        (__attribute__((address_space(3))) unsigned int*)(unsigned)(unsigned long long)l,
        16, 0, 0);
}

// ---------------------------------------------------------------- cast x -> bf16
__global__ __launch_bounds__(256) void cast_x(const float4* __restrict__ x,
                                              u16* __restrict__ xb) {
    long i = (long)blockIdx.x * 256 + threadIdx.x;   // one float4 per thread
    float4 v = x[i];
    u16* o = xb + i * 4;
    o[0] = f2bf(v.x); o[1] = f2bf(v.y); o[2] = f2bf(v.z); o[3] = f2bf(v.w);
}

// ---------------------------------------------------------------- weight fold/transpose (f32 inputs)
__global__ __launch_bounds__(256) void fold_weights(
    const float* __restrict__ Wq, const float* __restrict__ Wk,
    const float* __restrict__ Wv, const float* __restrict__ Wo,
    const float* __restrict__ bq, const float* __restrict__ bk,
    const float* __restrict__ bv, const float* __restrict__ proj,
    u16* __restrict__ WallT, u16* __restrict__ WoT, float* __restrict__ bias_all)
{
    const int r = blockIdx.x;
    const int tid = threadIdx.x;
    if (r < 1024) {
        const float* W  = (r < 512) ? Wq : Wk;
        const float* bb = (r < 512) ? bq : bk;
        const int h = (r & 511) >> 5, f = r & 31;
        __shared__ float pcol[64];
        if (tid < 64) pcol[tid] = proj[tid * 32 + f];
        __syncthreads();
        for (int it = 0; it < 4; it++) {
            const int kin = it * 256 + tid;
            const float* wrow = W + (long)kin * 1024 + h * 64;
            float acc = 0.f;
            #pragma unroll
            for (int d = 0; d < 64; d += 4) {
                float4 w = *(const float4*)(wrow + d);
                acc += w.x * pcol[d] + w.y * pcol[d + 1] + w.z * pcol[d + 2] + w.w * pcol[d + 3];
            }
            WallT[(long)r * 1024 + kin] = f2bf(acc);
        }
        if (tid == 0) {
            float a = 0.f;
            for (int d = 0; d < 64; d++) a += bb[h * 64 + d] * pcol[d];
            bias_all[r] = a;
        }
    } else if (r < 2048) {
        const int c = r - 1024;
        for (int it = 0; it < 4; it++) {
            const int kin = it * 256 + tid;
            WallT[(long)r * 1024 + kin] = f2bf(Wv[(long)kin * 1024 + c]);
        }
        if (tid == 0) bias_all[r] = bv[c];
    } else {
        const int c = r - 2048;
        for (int it = 0; it < 4; it++) {
            const int kin = it * 256 + tid;
            WoT[(long)c * 1024 + kin] = f2bf(Wo[(long)kin * 1024 + c]);
        }
    }
}

// ---------------------------------------------------------------- 128x128 bf16 MFMA GEMM body, B transposed [N][K]
// XOR-swizzled LDS: slot c of row r holds global k-chunk c ^ ((r>>1)&3).
// Staging LDS writes stay lane-contiguous (global_load_lds requirement);
// only the per-lane GLOBAL address is permuted. Fragment ds_reads XOR the
// selector back -> per-phase bank spread 8 groups x2 = 2-way (free, m136).
template<int NCOLS, bool RELUQK, typename OutT>
__device__ inline void gemm_body(
    const u16* __restrict__ A, const u16* __restrict__ Bt,
    const float* __restrict__ bias, OutT* __restrict__ C)
{
    constexpr int K = 1024;
    __shared__ alignas(16) u16 As[128 * 32];   // [m][k-slot] row-major
    __shared__ alignas(16) u16 Bs[128 * 32];   // [n][k-slot] row-major
    const int tid = threadIdx.x;
    const int wave = tid >> 6, lane = tid & 63;
    const int wm = wave >> 1, wn = wave & 1;
    const long m0 = (long)blockIdx.x * 128;
    const long n0 = (long)blockIdx.y * 128;

    // staging: lane covers row wave*16+(lane>>2); fetches swizzled global chunk
    const int gch = (lane & 3) ^ ((lane >> 3) & 3);
    const u16* Ab = A  + (m0 + wave * 16 + (lane >> 2)) * K + gch * 8;
    const u16* Bb = Bt + (n0 + wave * 16 + (lane >> 2)) * K + gch * 8;
    u16* lA = &As[(wave * 16) * 32];
    u16* lB = &Bs[(wave * 16) * 32];

    f32x4 acc[4][4] = {};

    // fragment read: row m=lane&15, global chunk kc=lane>>4 lives at slot kc^sel
    const int m = lane & 15, kc = lane >> 4;
    const int sel = (m >> 1) & 3;              // invariant under row += 16/64
    const int ar = (wm * 64 + m) * 32 + ((kc ^ sel) * 8);
    const int br = (wn * 64 + m) * 32 + ((kc ^ sel) * 8);

    for (int k0 = 0; k0 < K; k0 += 32) {
        __syncthreads();
        gload_lds16(Ab + k0,           lA);
        gload_lds16(Ab + k0 + 64 * K,  lA + 64 * 32);
        gload_lds16(Bb + k0,           lB);
        gload_lds16(Bb + k0 + 64 * K,  lB + 64 * 32);
        __syncthreads();

        bf16x8 af[4], bfv[4];
        #pragma unroll
        for (int t = 0; t < 4; t++) {
            af[t]  = *(const bf16x8*)&As[ar + t * 16 * 32];
            bfv[t] = *(const bf16x8*)&Bs[br + t * 16 * 32];
        }
        #pragma unroll
        for (int mt = 0; mt < 4; mt++)
            #pragma unroll
            for (int nt = 0; nt < 4; nt++)
                acc[mt][nt] = __builtin_amdgcn_mfma_f32_16x16x32_bf16(
                    af[mt], bfv[nt], acc[mt][nt], 0, 0, 0);
    }

    // epilogue: C/D layout col=lane&15, row=(lane>>4)*4+reg  [m89/m91]
    const bool dorelu = RELUQK && (n0 < 1024);
    const int cr = wm * 64 + (lane >> 4) * 4;
    const int cc = wn * 64 + (lane & 15);
    #pragma unroll
    for (int nt = 0; nt < 4; nt++) {
        const long gcol = n0 + cc + nt * 16;
        const float bval = bias[gcol];
        #pragma unroll
        for (int mt = 0; mt < 4; mt++) {
            #pragma unroll
            for (int r = 0; r < 4; r++) {
                float c = acc[mt][nt][r] + bval;
                if (dorelu) c = fmaxf(c, 0.f) * 0.17677669529663687f;  // 1/sqrt(32)
                OutT* dst = &C[(m0 + cr + mt * 16 + r) * (long)NCOLS + gcol];
                if constexpr (sizeof(OutT) == 2) *dst = f2bf(c);
                else                             *dst = c;
            }
        }
    }
}

// Distinct names so the profiler separates the two GEMMs.
__global__ __launch_bounds__(256) void gemm_qkv(
    const u16* __restrict__ A, const u16* __restrict__ Bt,
    const float* __restrict__ bias, u16* __restrict__ C)
{
    gemm_body<2048, true, u16>(A, Bt, bias, C);
}

__global__ __launch_bounds__(256) void gemm_out(
    const u16* __restrict__ A, const u16* __restrict__ Bt,
    const float* __restrict__ bias, float* __restrict__ C)
{
    gemm_body<1024, false, float>(A, Bt, bias, C);
}

// ---------------------------------------------------------------- kv[b,h,f,d] + ksum[b,h,f]
__global__ __launch_bounds__(256) void kv_kernel(const u16* __restrict__ Y,
                                                 float* __restrict__ kv,
                                                 float* __restrict__ ksum)
{
    const int bh = blockIdx.x;       // 0..63
    const int chunk = blockIdx.y;    // 0..15  (256 rows each)
    const int b = bh >> 4, h = bh & 15;
    const int tid = threadIdx.x;
    const int f = tid >> 3, dg = (tid & 7) * 8;
    const long rbase = (long)(b * 4096 + chunk * 256) * 2048;
    const u16* kp = Y + rbase + 512  + h * 32 + f;
    const u16* vp = Y + rbase + 1024 + h * 64 + dg;
    float acc[8] = {};
    float ks = 0.f;
    for (int n = 0; n < 256; n++) {
        float kf = bf2f(*kp);
        bf16x8 vv = *(const bf16x8*)vp;
        #pragma unroll
        for (int j = 0; j < 8; j++) acc[j] += kf * bf2f((u16)vv[j]);
        ks += kf;
        kp += 2048; vp += 2048;
    }
    float* kvp = kv + ((long)bh * 32 + f) * 64 + dg;
    #pragma unroll
    for (int j = 0; j < 8; j++) atomicAdd(&kvp[j], acc[j]);
    if ((tid & 7) == 0) atomicAdd(&ksum[bh * 32 + f], ks);
}

// ---------------------------------------------------------------- attn v2: block-tiled, kv in registers
__global__ __launch_bounds__(256) void attn_v2(const u16* __restrict__ Y,
                                               const float* __restrict__ kv,
                                               const float* __restrict__ ksum,
                                               u16* __restrict__ attn)
{
    __shared__ alignas(16) u16 qs[64 * 32];   // [local_row][f]
    __shared__ float zs[64];                  // 1/(den+eps) per local row
    const int tid = threadIdx.x;
    const int bh = blockIdx.x;
    const int b = bh >> 4, h = bh & 15;
    const long row0 = (long)b * 4096 + (long)blockIdx.y * 64;

    // stage q tile: one bf16x8 per thread
    {
        const int lr = tid >> 2, c = (tid & 3) * 8;
        *(bf16x8*)&qs[lr * 32 + c] =
            *(const bf16x8*)(Y + (row0 + lr) * 2048 + h * 32 + c);
    }

    const int wave = tid >> 6, lane = tid & 63;
    const float* kvg = kv + (long)bh * 2048 + lane;
    float kvreg[32];
    #pragma unroll
    for (int ff = 0; ff < 32; ff++) kvreg[ff] = kvg[ff * 64];

    __syncthreads();

    // denominators
    {
        const int lr = wave * 16 + (lane & 15);
        const float* ks = ksum + bh * 32;
        float den = 0.f;
        #pragma unroll
        for (int fc = 0; fc < 4; fc++) {
            bf16x8 qv = *(const bf16x8*)&qs[lr * 32 + fc * 8];
            #pragma unroll
            for (int j = 0; j < 8; j++) den += bf2f((u16)qv[j]) * ks[fc * 8 + j];
        }
        if (lane < 16) zs[lr] = 1.f / (den + 1e-8f);
    }
    __syncthreads();

    #pragma unroll
    for (int rg = 0; rg < 4; rg++) {
        const int lr0 = wave * 16 + rg * 4;
        float acc0 = 0.f, acc1 = 0.f, acc2 = 0.f, acc3 = 0.f;
        #pragma unroll
        for (int fc = 0; fc < 4; fc++) {
            bf16x8 q0 = *(const bf16x8*)&qs[(lr0 + 0) * 32 + fc * 8];
            bf16x8 q1 = *(const bf16x8*)&qs[(lr0 + 1) * 32 + fc * 8];
            bf16x8 q2 = *(const bf16x8*)&qs[(lr0 + 2) * 32 + fc * 8];
            bf16x8 q3 = *(const bf16x8*)&qs[(lr0 + 3) * 32 + fc * 8];
            #pragma unroll
            for (int j = 0; j < 8; j++) {
                const float kvf = kvreg[fc * 8 + j];
                acc0 += bf2f((u16)q0[j]) * kvf;
                acc1 += bf2f((u16)q1[j]) * kvf;
                acc2 += bf2f((u16)q2[j]) * kvf;
                acc3 += bf2f((u16)q3[j]) * kvf;
            }
        }
        u16* op = attn + (row0 + lr0) * 1024 + h * 64 + lane;
        op[0]        = f2bf(acc0 * zs[lr0 + 0]);
        op[1024]     = f2bf(acc1 * zs[lr0 + 1]);
        op[2 * 1024] = f2bf(acc2 * zs[lr0 + 2]);
        op[3 * 1024] = f2bf(acc3 * zs[lr0 + 3]);
    }
}

// ---------------------------------------------------------------- launch
extern "C" void kernel_launch(void* const* d_in, const int* in_sizes, int n_in,
                              void* d_out, int out_size, void* d_ws, size_t ws_size,
                              hipStream_t stream)
{
    const float* x    = (const float*)d_in[0];
    const float* Wq   = (const float*)d_in[1];
    const float* bq   = (const float*)d_in[2];
    const float* Wk   = (const float*)d_in[3];
    const float* bk   = (const float*)d_in[4];
    const float* Wv   = (const float*)d_in[5];
    const float* bv   = (const float*)d_in[6];
    const float* proj = (const float*)d_in[7];
    const float* Wo   = (const float*)d_in[8];
    const float* bo   = (const float*)d_in[9];

    char* w = (char*)d_ws;
    u16*   xbf   = (u16*)  (w);                    // 33,554,432 B  (also attn)
    u16*   attn  = (u16*)  (w);                    // alias of xbf
    u16*   wallT = (u16*)  (w + 33554432);         //  4,194,304 B
    u16*   woT   = (u16*)  (w + 37748736);         //  2,097,152 B
    float* bias  = (float*)(w + 39845888);         //      8,192 B
    float* kv    = (float*)(w + 39854080);         //    524,288 B
    float* ksum  = (float*)(w + 40378368);         //      8,192 B
    u16*   Y     = (u16*)  (w + 40386560);         // 67,108,864 B  (~104.5 MB)

    hipMemsetAsync(kv, 0, 524288 + 8192, stream);  // kv + ksum contiguous

    cast_x<<<16384, 256, 0, stream>>>((const float4*)x, xbf);

    fold_weights<<<3072, 256, 0, stream>>>(Wq, Wk, Wv, Wo, bq, bk, bv, proj,
                                           wallT, woT, bias);

    gemm_qkv<<<dim3(128, 16), 256, 0, stream>>>(xbf, wallT, bias, Y);

    kv_kernel<<<dim3(64, 16), 256, 0, stream>>>(Y, kv, ksum);

    attn_v2<<<dim3(64, 64), 256, 0, stream>>>(Y, kv, ksum, attn);

    gemm_out<<<dim3(128, 8), 256, 0, stream>>>(attn, woT, bo, (float*)d_out);
}

// Round 7
// 431.959 us; speedup vs baseline: 1.5606x; 1.1056x over previous
//
#include <hip/hip_runtime.h>

typedef unsigned short u16;
typedef __attribute__((ext_vector_type(8))) short bf16x8;
typedef __attribute__((ext_vector_type(4))) float f32x4;

__device__ inline float bf2f(u16 u) {
    unsigned v = ((unsigned)u) << 16;
    return __builtin_bit_cast(float, v);
}
__device__ inline u16 f2bf(float f) {
    unsigned u = __builtin_bit_cast(unsigned, f);
    u += 0x7fff + ((u >> 16) & 1);   // RNE
    return (u16)(u >> 16);
}

// async global->LDS, 16B per lane. LDS dest = wave-uniform base + lane*16.
__device__ inline void gload_lds16(const void* g, void* l) {
    __builtin_amdgcn_global_load_lds(
        (const __attribute__((address_space(1))) unsigned int*)(unsigned long long)g,
        (__attribute__((address_space(3))) unsigned int*)(unsigned)(unsigned long long)l,
        16, 0, 0);
}

// ---------------------------------------------------------------- cast x -> bf16 (8 floats/thread, one 16B store)
__global__ __launch_bounds__(256) void cast_x(const float4* __restrict__ x,
                                              bf16x8* __restrict__ xb) {
    long i = (long)blockIdx.x * 256 + threadIdx.x;
    float4 v0 = x[2 * i];
    float4 v1 = x[2 * i + 1];
    bf16x8 o;
    o[0] = (short)f2bf(v0.x); o[1] = (short)f2bf(v0.y);
    o[2] = (short)f2bf(v0.z); o[3] = (short)f2bf(v0.w);
    o[4] = (short)f2bf(v1.x); o[5] = (short)f2bf(v1.y);
    o[6] = (short)f2bf(v1.z); o[7] = (short)f2bf(v1.w);
    xb[i] = o;
}

// ---------------------------------------------------------------- weight fold/transpose (f32 inputs)
__global__ __launch_bounds__(256) void fold_weights(
    const float* __restrict__ Wq, const float* __restrict__ Wk,
    const float* __restrict__ Wv, const float* __restrict__ Wo,
    const float* __restrict__ bq, const float* __restrict__ bk,
    const float* __restrict__ bv, const float* __restrict__ proj,
    u16* __restrict__ WallT, u16* __restrict__ WoT, float* __restrict__ bias_all)
{
    const int r = blockIdx.x;
    const int tid = threadIdx.x;
    if (r < 1024) {
        const float* W  = (r < 512) ? Wq : Wk;
        const float* bb = (r < 512) ? bq : bk;
        const int h = (r & 511) >> 5, f = r & 31;
        __shared__ float pcol[64];
        if (tid < 64) pcol[tid] = proj[tid * 32 + f];
        __syncthreads();
        for (int it = 0; it < 4; it++) {
            const int kin = it * 256 + tid;
            const float* wrow = W + (long)kin * 1024 + h * 64;
            float acc = 0.f;
            #pragma unroll
            for (int d = 0; d < 64; d += 4) {
                float4 w = *(const float4*)(wrow + d);
                acc += w.x * pcol[d] + w.y * pcol[d + 1] + w.z * pcol[d + 2] + w.w * pcol[d + 3];
            }
            WallT[(long)r * 1024 + kin] = f2bf(acc);
        }
        if (tid == 0) {
            float a = 0.f;
            for (int d = 0; d < 64; d++) a += bb[h * 64 + d] * pcol[d];
            bias_all[r] = a;
        }
    } else if (r < 2048) {
        const int c = r - 1024;
        for (int it = 0; it < 4; it++) {
            const int kin = it * 256 + tid;
            WallT[(long)r * 1024 + kin] = f2bf(Wv[(long)kin * 1024 + c]);
        }
        if (tid == 0) bias_all[r] = bv[c];
    } else {
        const int c = r - 2048;
        for (int it = 0; it < 4; it++) {
            const int kin = it * 256 + tid;
            WoT[(long)c * 1024 + kin] = f2bf(Wo[(long)kin * 1024 + c]);
        }
    }
}

// ---------------------------------------------------------------- 128x128 bf16 MFMA GEMM body, B transposed [N][K]
// XOR-swizzled LDS (bank-conflict-free fragment reads, verified 8.4M -> 0).
template<int NCOLS, bool RELUQK, typename OutT>
__device__ inline void gemm_body(
    const u16* __restrict__ A, const u16* __restrict__ Bt,
    const float* __restrict__ bias, OutT* __restrict__ C)
{
    constexpr int K = 1024;
    __shared__ alignas(16) u16 As[128 * 32];   // [m][k-slot] row-major
    __shared__ alignas(16) u16 Bs[128 * 32];   // [n][k-slot] row-major
    const int tid = threadIdx.x;
    const int wave = tid >> 6, lane = tid & 63;
    const int wm = wave >> 1, wn = wave & 1;
    const long m0 = (long)blockIdx.x * 128;
    const long n0 = (long)blockIdx.y * 128;

    const int gch = (lane & 3) ^ ((lane >> 3) & 3);
    const u16* Ab = A  + (m0 + wave * 16 + (lane >> 2)) * K + gch * 8;
    const u16* Bb = Bt + (n0 + wave * 16 + (lane >> 2)) * K + gch * 8;
    u16* lA = &As[(wave * 16) * 32];
    u16* lB = &Bs[(wave * 16) * 32];

    f32x4 acc[4][4] = {};

    const int m = lane & 15, kc = lane >> 4;
    const int sel = (m >> 1) & 3;
    const int ar = (wm * 64 + m) * 32 + ((kc ^ sel) * 8);
    const int br = (wn * 64 + m) * 32 + ((kc ^ sel) * 8);

    for (int k0 = 0; k0 < K; k0 += 32) {
        __syncthreads();
        gload_lds16(Ab + k0,           lA);
        gload_lds16(Ab + k0 + 64 * K,  lA + 64 * 32);
        gload_lds16(Bb + k0,           lB);
        gload_lds16(Bb + k0 + 64 * K,  lB + 64 * 32);
        __syncthreads();

        bf16x8 af[4], bfv[4];
        #pragma unroll
        for (int t = 0; t < 4; t++) {
            af[t]  = *(const bf16x8*)&As[ar + t * 16 * 32];
            bfv[t] = *(const bf16x8*)&Bs[br + t * 16 * 32];
        }
        #pragma unroll
        for (int mt = 0; mt < 4; mt++)
            #pragma unroll
            for (int nt = 0; nt < 4; nt++)
                acc[mt][nt] = __builtin_amdgcn_mfma_f32_16x16x32_bf16(
                    af[mt], bfv[nt], acc[mt][nt], 0, 0, 0);
    }

    const bool dorelu = RELUQK && (n0 < 1024);
    const int cr = wm * 64 + (lane >> 4) * 4;
    const int cc = wn * 64 + (lane & 15);
    #pragma unroll
    for (int nt = 0; nt < 4; nt++) {
        const long gcol = n0 + cc + nt * 16;
        const float bval = bias[gcol];
        #pragma unroll
        for (int mt = 0; mt < 4; mt++) {
            #pragma unroll
            for (int r = 0; r < 4; r++) {
                float c = acc[mt][nt][r] + bval;
                if (dorelu) c = fmaxf(c, 0.f) * 0.17677669529663687f;  // 1/sqrt(32)
                OutT* dst = &C[(m0 + cr + mt * 16 + r) * (long)NCOLS + gcol];
                if constexpr (sizeof(OutT) == 2) *dst = f2bf(c);
                else                             *dst = c;
            }
        }
    }
}

__global__ __launch_bounds__(256) void gemm_qkv(
    const u16* __restrict__ A, const u16* __restrict__ Bt,
    const float* __restrict__ bias, u16* __restrict__ C)
{
    gemm_body<2048, true, u16>(A, Bt, bias, C);
}

__global__ __launch_bounds__(256) void gemm_out(
    const u16* __restrict__ A, const u16* __restrict__ Bt,
    const float* __restrict__ bias, float* __restrict__ C)
{
    gemm_body<1024, false, float>(A, Bt, bias, C);
}

// ---------------------------------------------------------------- kv v3: LDS k-tile, 64-row chunks, partials (no atomics)
// grid (bh=64, chunk=64). part_kv[bh][chunk][f][d], part_ks[bh][chunk][f].
__global__ __launch_bounds__(256) void kv_v3(const u16* __restrict__ Y,
                                             float* __restrict__ part_kv,
                                             float* __restrict__ part_ks)
{
    __shared__ alignas(16) u16 ks[64 * 32];   // [local_row][f]
    const int bh = blockIdx.x, c = blockIdx.y;
    const int b = bh >> 4, h = bh & 15;
    const int tid = threadIdx.x;
    const long rbase = (long)b * 4096 + (long)c * 64;

    // stage k' tile: one bf16x8 per thread
    {
        const int lr = tid >> 2, cc = (tid & 3) * 8;
        *(bf16x8*)&ks[lr * 32 + cc] =
            *(const bf16x8*)(Y + (rbase + lr) * 2048 + 512 + h * 32 + cc);
    }
    __syncthreads();

    const int f = tid >> 3, dg = (tid & 7) * 8;
    const u16* vp = Y + rbase * 2048 + 1024 + h * 64 + dg;
    float acc[8] = {};
    float ksacc = 0.f;
    #pragma unroll 4
    for (int n = 0; n < 64; n++) {
        const float kf = bf2f(ks[n * 32 + f]);
        bf16x8 vv = *(const bf16x8*)(vp + (long)n * 2048);
        #pragma unroll
        for (int j = 0; j < 8; j++) acc[j] += kf * bf2f((u16)vv[j]);
        ksacc += kf;
    }

    float* o = part_kv + (((long)bh * 64 + c) * 32 + f) * 64 + dg;
    *(f32x4*)o       = f32x4{acc[0], acc[1], acc[2], acc[3]};
    *(f32x4*)(o + 4) = f32x4{acc[4], acc[5], acc[6], acc[7]};
    if ((tid & 7) == 0) part_ks[(bh * 64 + c) * 32 + f] = ksacc;
}

// reduce 64 partials -> kv[bh][f][d] (blocks 0..511) and ksum[bh][f] (512..519)
__global__ __launch_bounds__(256) void kv_reduce(const float* __restrict__ part_kv,
                                                 const float* __restrict__ part_ks,
                                                 float* __restrict__ kv,
                                                 float* __restrict__ ksum)
{
    const int idx = blockIdx.x * 256 + threadIdx.x;
    if (blockIdx.x < 512) {                       // 131072 kv elements
        const int bh = idx >> 11, off = idx & 2047;
        const float* p = part_kv + (long)bh * 131072 + off;
        float s = 0.f;
        #pragma unroll 8
        for (int c = 0; c < 64; c++) s += p[c * 2048];
        kv[idx] = s;
    } else {                                      // 2048 ksum elements
        const int i2 = idx - 512 * 256;
        const int bh = i2 >> 5, f = i2 & 31;
        const float* p = part_ks + bh * 64 * 32 + f;
        float s = 0.f;
        #pragma unroll 8
        for (int c = 0; c < 64; c++) s += p[c * 32];
        ksum[i2] = s;
    }
}

// ---------------------------------------------------------------- attn v2: block-tiled, kv in registers
__global__ __launch_bounds__(256) void attn_v2(const u16* __restrict__ Y,
                                               const float* __restrict__ kv,
                                               const float* __restrict__ ksum,
                                               u16* __restrict__ attn)
{
    __shared__ alignas(16) u16 qs[64 * 32];   // [local_row][f]
    __shared__ float zs[64];                  // 1/(den+eps) per local row
    const int tid = threadIdx.x;
    const int bh = blockIdx.x;
    const int b = bh >> 4, h = bh & 15;
    const long row0 = (long)b * 4096 + (long)blockIdx.y * 64;

    {
        const int lr = tid >> 2, c = (tid & 3) * 8;
        *(bf16x8*)&qs[lr * 32 + c] =
            *(const bf16x8*)(Y + (row0 + lr) * 2048 + h * 32 + c);
    }

    const int wave = tid >> 6, lane = tid & 63;
    const float* kvg = kv + (long)bh * 2048 + lane;
    float kvreg[32];
    #pragma unroll
    for (int ff = 0; ff < 32; ff++) kvreg[ff] = kvg[ff * 64];

    __syncthreads();

    {
        const int lr = wave * 16 + (lane & 15);
        const float* ks = ksum + bh * 32;
        float den = 0.f;
        #pragma unroll
        for (int fc = 0; fc < 4; fc++) {
            bf16x8 qv = *(const bf16x8*)&qs[lr * 32 + fc * 8];
            #pragma unroll
            for (int j = 0; j < 8; j++) den += bf2f((u16)qv[j]) * ks[fc * 8 + j];
        }
        if (lane < 16) zs[lr] = 1.f / (den + 1e-8f);
    }
    __syncthreads();

    #pragma unroll
    for (int rg = 0; rg < 4; rg++) {
        const int lr0 = wave * 16 + rg * 4;
        float acc0 = 0.f, acc1 = 0.f, acc2 = 0.f, acc3 = 0.f;
        #pragma unroll
        for (int fc = 0; fc < 4; fc++) {
            bf16x8 q0 = *(const bf16x8*)&qs[(lr0 + 0) * 32 + fc * 8];
            bf16x8 q1 = *(const bf16x8*)&qs[(lr0 + 1) * 32 + fc * 8];
            bf16x8 q2 = *(const bf16x8*)&qs[(lr0 + 2) * 32 + fc * 8];
            bf16x8 q3 = *(const bf16x8*)&qs[(lr0 + 3) * 32 + fc * 8];
            #pragma unroll
            for (int j = 0; j < 8; j++) {
                const float kvf = kvreg[fc * 8 + j];
                acc0 += bf2f((u16)q0[j]) * kvf;
                acc1 += bf2f((u16)q1[j]) * kvf;
                acc2 += bf2f((u16)q2[j]) * kvf;
                acc3 += bf2f((u16)q3[j]) * kvf;
            }
        }
        u16* op = attn + (row0 + lr0) * 1024 + h * 64 + lane;
        op[0]        = f2bf(acc0 * zs[lr0 + 0]);
        op[1024]     = f2bf(acc1 * zs[lr0 + 1]);
        op[2 * 1024] = f2bf(acc2 * zs[lr0 + 2]);
        op[3 * 1024] = f2bf(acc3 * zs[lr0 + 3]);
    }
}

// ---------------------------------------------------------------- launch
extern "C" void kernel_launch(void* const* d_in, const int* in_sizes, int n_in,
                              void* d_out, int out_size, void* d_ws, size_t ws_size,
                              hipStream_t stream)
{
    const float* x    = (const float*)d_in[0];
    const float* Wq   = (const float*)d_in[1];
    const float* bq   = (const float*)d_in[2];
    const float* Wk   = (const float*)d_in[3];
    const float* bk   = (const float*)d_in[4];
    const float* Wv   = (const float*)d_in[5];
    const float* bv   = (const float*)d_in[6];
    const float* proj = (const float*)d_in[7];
    const float* Wo   = (const float*)d_in[8];
    const float* bo   = (const float*)d_in[9];

    // Region w+0 (33.5 MB) is time-multiplexed: xbf (dies at gemm_qkv) ->
    // part_kv (kv_v3..kv_reduce) -> attn (attn_v2..gemm_out).
    char* w = (char*)d_ws;
    u16*   xbf     = (u16*)  (w);                  // 33,554,432 B
    float* part_kv = (float*)(w);                  // alias
    u16*   attn    = (u16*)  (w);                  // alias
    u16*   wallT   = (u16*)  (w + 33554432);       //  4,194,304 B
    u16*   woT     = (u16*)  (w + 37748736);       //  2,097,152 B
    float* bias    = (float*)(w + 39845888);       //      8,192 B
    float* kv      = (float*)(w + 39854080);       //    524,288 B
    float* ksum    = (float*)(w + 40378368);       //      8,192 B
    u16*   Y       = (u16*)  (w + 40386560);       // 67,108,864 B
    float* part_ks = (float*)(w + 107495424);      //    524,288 B (~108 MB total)

    cast_x<<<8192, 256, 0, stream>>>((const float4*)x, (bf16x8*)xbf);

    fold_weights<<<3072, 256, 0, stream>>>(Wq, Wk, Wv, Wo, bq, bk, bv, proj,
                                           wallT, woT, bias);

    gemm_qkv<<<dim3(128, 16), 256, 0, stream>>>(xbf, wallT, bias, Y);

    kv_v3<<<dim3(64, 64), 256, 0, stream>>>(Y, part_kv, part_ks);

    kv_reduce<<<520, 256, 0, stream>>>(part_kv, part_ks, kv, ksum);

    attn_v2<<<dim3(64, 64), 256, 0, stream>>>(Y, kv, ksum, attn);

    gemm_out<<<dim3(128, 8), 256, 0, stream>>>(attn, woT, bo, (float*)d_out);
}